// Round 7
// baseline (1950.983 us; speedup 1.0000x reference)
//
// GPT-2 (124M) forward on MI355X — round 11.
// Base = round 10 (1938us). Single change: lm_head switches from the 256x256
// 8-phase gemm256_kernel (1 block/CU: 128KB LDS + 240 regs -> no co-resident
// block, 27% MfmaUtil, 247us pinned for 6 rounds) to the verified 128x128
// 2-barrier gemm_kernel<3,128>: 48KB LDS -> 3 blocks/CU, cross-block overlap
// instead of intra-block pipelining. Grid 393x16=6288 blocks; XCD chunks share
// B panels (192KB, L2-resident) and sweep A (3MB, fits per-XCD L2).
#include <hip/hip_runtime.h>
#include <hip/hip_bf16.h>
#include <stdint.h>

#define NL 12
#define E  768
#define TS 1024
#define BB 2
#define MM 2048     // B*T
#define NH 12
#define DH 64
#define FF 3072
#define Q3 2304
#define NV 50257

typedef __attribute__((ext_vector_type(4))) float  f32x4;
typedef __attribute__((ext_vector_type(8))) __bf16 bf16x8;

__device__ __forceinline__ unsigned short f2bf(float f) {
  unsigned u = __float_as_uint(f);
  unsigned r = u + 0x7fffu + ((u >> 16) & 1u);
  return (unsigned short)(r >> 16);
}

__device__ __forceinline__ f32x4 mfma16(bf16x8 a, bf16x8 b, f32x4 c) {
  return __builtin_amdgcn_mfma_f32_16x16x32_bf16(a, b, c, 0, 0, 0);
}

typedef const __attribute__((address_space(1))) void gvoid_t;
typedef __attribute__((address_space(3))) void lvoid_t;
__device__ __forceinline__ void gld_lds16(const void* g, void* l) {
  __builtin_amdgcn_global_load_lds((gvoid_t*)(uintptr_t)g,
                                   (lvoid_t*)(uint32_t)(uintptr_t)l, 16, 0, 0);
}

__device__ __forceinline__ float gelu_f(float x) {
  // 0.5x(1+tanh(t)) == x*sigmoid(2t)
  float t2 = 1.5957691216057308f * (x + 0.044715f * x * x * x);
  return x / (1.0f + __expf(-t2));
}

// bijective XCD-chunked swizzle (m204): each of 8 XCDs gets a contiguous chunk.
__device__ __forceinline__ unsigned xcd_swz(unsigned orig, unsigned nwg) {
  unsigned q = nwg >> 3, r = nwg & 7;
  unsigned xcd = orig & 7, i = orig >> 3;
  unsigned base = (xcd < r) ? xcd * (q + 1) : r * (q + 1) + (xcd - r) * q;
  return base + i;
}

// ---------------- cast fp32 -> bf16 (wte, grid-stride float4) ----------------
__global__ __launch_bounds__(256) void cast_kernel(const float* __restrict__ src,
                                                   unsigned short* __restrict__ dst, size_t n4) {
  size_t i = (size_t)blockIdx.x * blockDim.x + threadIdx.x;
  size_t stride = (size_t)gridDim.x * blockDim.x;
  for (; i < n4; i += stride) {
    float4 v = ((const float4*)src)[i];
    uint2 o;
    o.x = (unsigned)f2bf(v.x) | ((unsigned)f2bf(v.y) << 16);
    o.y = (unsigned)f2bf(v.z) | ((unsigned)f2bf(v.w) << 16);
    ((uint2*)dst)[i] = o;
  }
}

// ------------- transpose W[K][N] fp32 -> Bt[N][K] bf16 (32x32 tiles) ---------
__global__ __launch_bounds__(256) void transpose_kernel(const float* __restrict__ src,
                                                        unsigned short* __restrict__ dst,
                                                        int K, int N, long sls, long dls) {
  __shared__ float tile[32][33];
  long z = blockIdx.z;
  const float* s = src + z * sls;
  unsigned short* d = dst + z * dls;
  int n0 = blockIdx.x * 32, k0 = blockIdx.y * 32;
  int tid = threadIdx.x;
  int r = tid >> 3, c4 = (tid & 7) * 4;
  float4 v = *(const float4*)(s + (size_t)(k0 + r) * N + n0 + c4);
  tile[r][c4] = v.x; tile[r][c4 + 1] = v.y; tile[r][c4 + 2] = v.z; tile[r][c4 + 3] = v.w;
  __syncthreads();
  unsigned short o[4];
  #pragma unroll
  for (int i = 0; i < 4; ++i) o[i] = f2bf(tile[c4 + i][r]);
  *(uint2*)(d + (size_t)(n0 + r) * K + k0 + c4) = *(uint2*)o;
}

// ---------------- embedding: x = wte[idx] + wpe (fp32) -----------------------
__global__ __launch_bounds__(192) void embed_kernel(const int* __restrict__ idx,
                                                    const float* __restrict__ wte,
                                                    const float* __restrict__ wpe,
                                                    float* __restrict__ x) {
  int row = blockIdx.x, tid = threadIdx.x;
  int t = row & (TS - 1);
  int id = idx[row];
  float4 a = *(const float4*)(wte + (size_t)id * E + tid * 4);
  float4 p = *(const float4*)(wpe + (size_t)t * E + tid * 4);
  float4 r;
  r.x = a.x + p.x; r.y = a.y + p.y; r.z = a.z + p.z; r.w = a.w + p.w;
  *(float4*)(x + (size_t)row * E + tid * 4) = r;
}

// ---------------- LayerNorm (fp32 in, bf16 out), one WAVE per row ------------
// 12 floats/lane (3x float4), 6-step shfl_xor butterflies, no LDS/barriers.
__global__ __launch_bounds__(256) void ln_kernel(const float* __restrict__ x,
                                                 const float* __restrict__ w,
                                                 const float* __restrict__ bb,
                                                 unsigned short* __restrict__ out) {
  int wv = threadIdx.x >> 6, l = threadIdx.x & 63;
  int row = blockIdx.x * 4 + wv;
  const float* xr = x + (size_t)row * E;
  int c0 = l * 4;
  float4 v0 = *(const float4*)(xr + c0);
  float4 v1 = *(const float4*)(xr + c0 + 256);
  float4 v2 = *(const float4*)(xr + c0 + 512);
  float s = v0.x + v0.y + v0.z + v0.w + v1.x + v1.y + v1.z + v1.w +
            v2.x + v2.y + v2.z + v2.w;
  #pragma unroll
  for (int sh = 32; sh >= 1; sh >>= 1) s += __shfl_xor(s, sh);
  float mu = s * (1.0f / E);
  float d[12] = {v0.x - mu, v0.y - mu, v0.z - mu, v0.w - mu,
                 v1.x - mu, v1.y - mu, v1.z - mu, v1.w - mu,
                 v2.x - mu, v2.y - mu, v2.z - mu, v2.w - mu};
  float q = 0.f;
  #pragma unroll
  for (int i = 0; i < 12; ++i) q += d[i] * d[i];
  #pragma unroll
  for (int sh = 32; sh >= 1; sh >>= 1) q += __shfl_xor(q, sh);
  float rs = rsqrtf(q * (1.0f / E) + 1e-5f);
  unsigned short* orow = out + (size_t)row * E;
  #pragma unroll
  for (int c = 0; c < 3; ++c) {
    float4 wc = *(const float4*)(w + c0 + c * 256);
    float4 bc = *(const float4*)(bb + c0 + c * 256);
    float o0 = d[c * 4 + 0] * rs * wc.x + bc.x;
    float o1 = d[c * 4 + 1] * rs * wc.y + bc.y;
    float o2 = d[c * 4 + 2] * rs * wc.z + bc.z;
    float o3 = d[c * 4 + 3] * rs * wc.w + bc.w;
    uint2 u;
    u.x = (unsigned)f2bf(o0) | ((unsigned)f2bf(o1) << 16);
    u.y = (unsigned)f2bf(o2) | ((unsigned)f2bf(o3) << 16);
    *(uint2*)(orow + c0 + c * 256) = u;
  }
}

// ---------------- 128-tile GEMM (layer GEMMs + lm_head) ----------------------
// Split-K via blockIdx.z (used for EPI=2): each z-slice covers K/gridDim.z,
// epilogue atomicAdds partials into resid; bias added by kz==0 only.
// EPI=3: fp32 output with gn<N tail guard, no bias (lm_head).
template <int EPI, int BM>
__global__ __launch_bounds__(256) void gemm_kernel(const unsigned short* __restrict__ A,
                                                   const unsigned short* __restrict__ Bt,
                                                   const float* __restrict__ bias,
                                                   void* __restrict__ outp,
                                                   float* __restrict__ resid,
                                                   unsigned short* __restrict__ vTout,
                                                   int M, int N, int K, int Brows, int ldc) {
  constexpr int MT = BM / 32;
  __shared__ char lA[BM * 128];
  __shared__ char lB[128 * 128];
  int tid = threadIdx.x;
  int w = tid >> 6, l = tid & 63, lg = l >> 4, lo = l & 15;

  unsigned nwg = gridDim.x * gridDim.y;
  unsigned orig = blockIdx.y * gridDim.x + blockIdx.x;
  unsigned wgid = xcd_swz(orig, nwg);
  unsigned bm = wgid % gridDim.y;
  unsigned bn = wgid / gridDim.y;
  int m0 = bm * BM, n0 = bn * 128;

  int kz = blockIdx.z;
  int kslice = K / gridDim.z;
  int kbeg = kz * kslice, kend = kbeg + kslice;

  int wrow = (w >> 1) * (BM / 2), wcol = (w & 1) * 64;
  f32x4 acc[MT][4];
  const f32x4 z4 = {0.f, 0.f, 0.f, 0.f};
  #pragma unroll
  for (int i = 0; i < MT; ++i)
    #pragma unroll
    for (int j = 0; j < 4; ++j) acc[i][j] = z4;

  for (int k0 = kbeg; k0 < kend; k0 += 64) {
    int sl = tid & 7;
    #pragma unroll
    for (int i = 0; i < BM / 32; ++i) {
      int r = i * 32 + (tid >> 3);
      int s = sl ^ (r & 7);
      gld_lds16(A + (size_t)(m0 + r) * K + k0 + s * 8, lA + r * 128 + sl * 16);
    }
    #pragma unroll
    for (int i = 0; i < 4; ++i) {
      int r = i * 32 + (tid >> 3);
      int s = sl ^ (r & 7);
      int rb = n0 + r;
      if (rb > Brows - 1) rb = Brows - 1;
      gld_lds16(Bt + (size_t)rb * K + k0 + s * 8, lB + r * 128 + sl * 16);
    }
    __syncthreads();
    #pragma unroll
    for (int kk = 0; kk < 2; ++kk) {
      bf16x8 af[MT], bfr[4];
      #pragma unroll
      for (int mt = 0; mt < MT; ++mt) {
        int r = wrow + mt * 16 + lo;
        af[mt] = *(const bf16x8*)(lA + r * 128 + (((kk * 4 + lg) ^ (r & 7)) << 4));
      }
      #pragma unroll
      for (int nt = 0; nt < 4; ++nt) {
        int r = wcol + nt * 16 + lo;
        bfr[nt] = *(const bf16x8*)(lB + r * 128 + (((kk * 4 + lg) ^ (r & 7)) << 4));
      }
      #pragma unroll
      for (int mt = 0; mt < MT; ++mt)
        #pragma unroll
        for (int nt = 0; nt < 4; ++nt) acc[mt][nt] = mfma16(af[mt], bfr[nt], acc[mt][nt]);
    }
    __syncthreads();
  }

  #pragma unroll
  for (int mt = 0; mt < MT; ++mt) {
    #pragma unroll
    for (int nt = 0; nt < 4; ++nt) {
      int gn = n0 + wcol + nt * 16 + lo;
      float bv = 0.f;
      if (EPI != 3 && bias != nullptr && !(EPI == 2 && kz != 0)) bv = bias[gn];
      float vv[4];
      int gm0 = m0 + wrow + mt * 16 + lg * 4;
      #pragma unroll
      for (int rr = 0; rr < 4; ++rr) vv[rr] = acc[mt][nt][rr] + bv;
      if constexpr (EPI == 0) {
        if (gn >= 2 * E) {
          int dcol = gn - 2 * E;
          int b = gm0 >> 10, t = gm0 & (TS - 1);
          size_t addr = (((size_t)(b * NH + (dcol >> 6)) * DH + (dcol & 63)) << 10) + t;
          uint2 u;
          u.x = (unsigned)f2bf(vv[0]) | ((unsigned)f2bf(vv[1]) << 16);
          u.y = (unsigned)f2bf(vv[2]) | ((unsigned)f2bf(vv[3]) << 16);
          *(uint2*)(vTout + addr) = u;
        } else {
          #pragma unroll
          for (int rr = 0; rr < 4; ++rr)
            ((unsigned short*)outp)[(size_t)(gm0 + rr) * ldc + gn] = f2bf(vv[rr]);
        }
      } else if constexpr (EPI == 1) {
        #pragma unroll
        for (int rr = 0; rr < 4; ++rr)
          ((unsigned short*)outp)[(size_t)(gm0 + rr) * ldc + gn] = f2bf(gelu_f(vv[rr]));
      } else if constexpr (EPI == 2) {
        #pragma unroll
        for (int rr = 0; rr < 4; ++rr) {
          size_t off = (size_t)(gm0 + rr) * ldc + gn;
          atomicAdd(&resid[off], vv[rr]);
        }
      } else {
        if (gn < N) {
          #pragma unroll
          for (int rr = 0; rr < 4; ++rr)
            ((float*)outp)[(size_t)(gm0 + rr) * ldc + gn] = vv[rr];
        }
      }
    }
  }
}

// ---------------- fused causal attention v2 ----------------------------------
// grid 384 blocks (XCD-grouped: 3 bh per XCD), 4 waves x 16 q-rows = 64 q/block.
// KVBLK=64; K,V staged via async global_load_lds, double-buffered (stage t+1
// before compute t; __syncthreads drains). 1 barrier/tile. Swapped QK^T;
// per-wave P in LDS (144B rows); O^T = V^T P^T.
__global__ __launch_bounds__(256) void attn_kernel(const unsigned short* __restrict__ qkv,
                                                   const unsigned short* __restrict__ vT,
                                                   unsigned short* __restrict__ y) {
  __shared__ char kbuf[2][8192];   // [64 kv][64 d] bf16, 8x16B slots/row, slot^=(row&7)
  __shared__ char vbuf[2][8192];   // [64 d][64 t] bf16, same swizzle
  __shared__ char pbuf[4][16 * 144];  // per-wave P [16 q][64 kv] bf16, 144B row stride

  int lin = blockIdx.x;                 // 384 = 8 XCDs * 48
  int nid = (lin & 7) * 48 + (lin >> 3);
  int bh = nid >> 4, qb = nid & 15;
  int b = bh / NH, h = bh - b * NH;
  int tid = threadIdx.x;
  int w = tid >> 6, l = tid & 63, lg = l >> 4, lo = l & 15;
  char* pw = pbuf[w];
  int qg = qb * 64 + w * 16 + lo;

  const unsigned short* qrow = qkv + (size_t)(b * TS + qg) * Q3 + h * DH;
  bf16x8 qf[2];
  qf[0] = *(const bf16x8*)(qrow + 8 * lg);
  qf[1] = *(const bf16x8*)(qrow + 32 + 8 * lg);

  const f32x4 z4 = {0.f, 0.f, 0.f, 0.f};
  f32x4 o[4] = {z4, z4, z4, z4};
  float m = -INFINITY, lsum = 0.f;

  const unsigned short* kbase = qkv + (size_t)b * TS * Q3 + E + h * DH;
  const unsigned short* vbase = vT + (size_t)bh * DH * TS;

  auto stage = [&](int p, int t0) {
    #pragma unroll
    for (int j = 0; j < 2; ++j) {
      int sid = tid + j * 256;
      int row = sid >> 3, sl = sid & 7;
      gld_lds16(kbase + (size_t)(t0 + row) * Q3 + ((sl ^ (row & 7)) << 3),
                kbuf[p] + sid * 16);
    }
    #pragma unroll
    for (int j = 0; j < 2; ++j) {
      int sid = tid + j * 256;
      int row = sid >> 3, sl = sid & 7;
      gld_lds16(vbase + (size_t)row * TS + t0 + ((sl ^ (row & 7)) << 3),
                vbuf[p] + sid * 16);
    }
  };

  int ntiles = qb + 1;
  stage(0, 0);
  __syncthreads();

  int p = 0;
  for (int it = 0; it < ntiles; ++it) {
    int t0 = it * 64;
    if (it + 1 < ntiles) stage(p ^ 1, t0 + 64);

    // QK^T: S^T fragment, q = lo, kv = t0 + kq*16 + lg*4 + rr
    f32x4 s[4] = {z4, z4, z4, z4};
    #pragma unroll
    for (int dk = 0; dk < 2; ++dk) {
      #pragma unroll
      for (int kq = 0; kq < 4; ++kq) {
        int row = kq * 16 + lo;
        bf16x8 kf = *(const bf16x8*)(kbuf[p] + row * 128 + (((dk * 4 + lg) ^ (row & 7)) << 4));
        s[kq] = mfma16(kf, qf[dk], s[kq]);
      }
    }
    // online softmax over 16 kv entries/lane (+ reduce across lg via shfl)
    float pe[16];
    float pmax = -INFINITY;
    #pragma unroll
    for (int kq = 0; kq < 4; ++kq)
      #pragma unroll
      for (int rr = 0; rr < 4; ++rr) {
        float v = s[kq][rr] * 0.125f;
        int kvg = t0 + kq * 16 + lg * 4 + rr;
        if (kvg > qg) v = -INFINITY;
        pe[kq * 4 + rr] = v;
        pmax = fmaxf(pmax, v);
      }
    pmax = fmaxf(pmax, __shfl_xor(pmax, 16));
    pmax = fmaxf(pmax, __shfl_xor(pmax, 32));
    float mn = fmaxf(m, pmax);
    float alpha = __expf(m - mn);
    float ps = 0.f;
    #pragma unroll
    for (int i = 0; i < 16; ++i) { pe[i] = __expf(pe[i] - mn); ps += pe[i]; }
    ps += __shfl_xor(ps, 16);
    ps += __shfl_xor(ps, 32);
    lsum = lsum * alpha + ps;
    m = mn;
    #pragma unroll
    for (int dt = 0; dt < 4; ++dt) o[dt] = o[dt] * alpha;
    // P -> LDS: row q=lo (144B stride), kv chunk kq*16+lg*4
    #pragma unroll
    for (int kq = 0; kq < 4; ++kq) {
      unsigned pa = (unsigned)f2bf(pe[kq * 4 + 0]) | ((unsigned)f2bf(pe[kq * 4 + 1]) << 16);
      unsigned pb = (unsigned)f2bf(pe[kq * 4 + 2]) | ((unsigned)f2bf(pe[kq * 4 + 3]) << 16);
      char* pp = pw + lo * 144 + kq * 32 + lg * 8;
      *(unsigned*)pp = pa;
      *(unsigned*)(pp + 4) = pb;
    }
    // PV: o^T[d][q] += V^T[d][kv] * P[kv][q], kv in 2 chunks of 32
    bf16x8 pf0 = *(const bf16x8*)(pw + lo * 144 + lg * 16);
    bf16x8 pf1 = *(const bf16x8*)(pw + lo * 144 + 64 + lg * 16);
    #pragma unroll
    for (int dt = 0; dt < 4; ++dt) {
      int row = dt * 16 + lo;
      bf16x8 vf0 = *(const bf16x8*)(vbuf[p] + row * 128 + ((lg ^ (row & 7)) << 4));
      bf16x8 vf1 = *(const bf16x8*)(vbuf[p] + row * 128 + (((4 + lg) ^ (row & 7)) << 4));
      o[dt] = mfma16(vf0, pf0, o[dt]);
      o[dt] = mfma16(vf1, pf1, o[dt]);
    }
    __syncthreads();   // drains vmcnt (staged loads) + lgkm; protects buffers
    p ^= 1;
  }

  float inv = 1.0f / lsum;
  unsigned short* yrow = y + (size_t)(b * TS + qg) * E + h * DH;
  #pragma unroll
  for (int dt = 0; dt < 4; ++dt) {
    uint2 u;
    u.x = (unsigned)f2bf(o[dt][0] * inv) | ((unsigned)f2bf(o[dt][1] * inv) << 16);
    u.y = (unsigned)f2bf(o[dt][2] * inv) | ((unsigned)f2bf(o[dt][3] * inv) << 16);
    *(uint2*)(yrow + dt * 16 + lg * 4) = u;
  }
}

// -----------------------------------------------------------------------------
extern "C" void kernel_launch(void* const* d_in, const int* in_sizes, int n_in,
                              void* d_out, int out_size, void* d_ws, size_t ws_size,
                              hipStream_t stream) {
  const int*   idx   = (const int*)  d_in[0];
  const float* wte   = (const float*)d_in[1];
  const float* wpe   = (const float*)d_in[2];
  const float* ln1w  = (const float*)d_in[3];
  const float* ln1b  = (const float*)d_in[4];
  const float* attnw = (const float*)d_in[5];
  const float* attnb = (const float*)d_in[6];
  const float* projw = (const float*)d_in[7];
  const float* projb = (const float*)d_in[8];
  const float* ln2w  = (const float*)d_in[9];
  const float* ln2b  = (const float*)d_in[10];
  const float* fcw   = (const float*)d_in[11];
  const float* fcb   = (const float*)d_in[12];
  const float* fcpw  = (const float*)d_in[13];
  const float* fcpb  = (const float*)d_in[14];
  const float* lnfw  = (const float*)d_in[15];
  const float* lnfb  = (const float*)d_in[16];

  char* ws = (char*)d_ws;
  size_t off = 0;
  auto alloc = [&](size_t bytes) -> char* {
    char* p = ws + off;
    off += (bytes + 255) & ~(size_t)255;
    return p;
  };

  const size_t szQkvT = (size_t)Q3 * E * 2;
  const size_t szProjT = (size_t)E * E * 2;
  const size_t szFcT = (size_t)FF * E * 2;
  const size_t szFcpT = (size_t)E * FF * 2;
  const size_t perL = szQkvT + szProjT + szFcT + szFcpT;
  const size_t szWte = (size_t)NV * E * 2;
  const size_t szActs = (size_t)MM * E * 4 + (size_t)MM * E * 2 + (size_t)MM * Q3 * 2 +
                        (size_t)BB * NH * DH * TS * 2 + (size_t)MM * E * 2 + (size_t)MM * FF * 2;
  bool big = ws_size >= szWte + NL * perL + szActs + (size_t)64 * 1024;
  size_t slots = big ? NL : 1;

  unsigned short* wteBf = (unsigned short*)alloc(szWte);
  unsigned short* qkvT  = (unsigned short*)alloc(slots * szQkvT);
  unsigned short* projT = (unsigned short*)alloc(slots * szProjT);
  unsigned short* fcT   = (unsigned short*)alloc(slots * szFcT);
  unsigned short* fcpT  = (unsigned short*)alloc(slots * szFcpT);
  float*          xf    = (float*)         alloc((size_t)MM * E * 4);
  unsigned short* hb    = (unsigned short*)alloc((size_t)MM * E * 2);
  unsigned short* qkvb  = (unsigned short*)alloc((size_t)MM * Q3 * 2);
  unsigned short* vTb   = (unsigned short*)alloc((size_t)BB * NH * DH * TS * 2);
  unsigned short* yb    = (unsigned short*)alloc((size_t)MM * E * 2);
  unsigned short* ffb   = (unsigned short*)alloc((size_t)MM * FF * 2);

  cast_kernel<<<2048, 256, 0, stream>>>(wte, wteBf, (size_t)NV * E / 4);

  if (big) {
    transpose_kernel<<<dim3(Q3 / 32, E / 32, NL), 256, 0, stream>>>(attnw, qkvT, E, Q3, (long)E * Q3, (long)Q3 * E);
    transpose_kernel<<<dim3(E / 32, E / 32, NL), 256, 0, stream>>>(projw, projT, E, E, (long)E * E, (long)E * E);
    transpose_kernel<<<dim3(FF / 32, E / 32, NL), 256, 0, stream>>>(fcw, fcT, E, FF, (long)E * FF, (long)FF * E);
    transpose_kernel<<<dim3(E / 32, FF / 32, NL), 256, 0, stream>>>(fcpw, fcpT, FF, E, (long)FF * E, (long)E * FF);
  }

  embed_kernel<<<MM, 192, 0, stream>>>(idx, wte, wpe, xf);

  for (int l = 0; l < NL; ++l) {
    unsigned short* qT  = qkvT  + (big ? (size_t)l * Q3 * E : 0);
    unsigned short* pT  = projT + (big ? (size_t)l * E * E : 0);
    unsigned short* fT  = fcT   + (big ? (size_t)l * FF * E : 0);
    unsigned short* fpT = fcpT  + (big ? (size_t)l * E * FF : 0);
    if (!big) {
      transpose_kernel<<<dim3(Q3 / 32, E / 32, 1), 256, 0, stream>>>(attnw + (size_t)l * E * Q3, qT, E, Q3, 0, 0);
      transpose_kernel<<<dim3(E / 32, E / 32, 1), 256, 0, stream>>>(projw + (size_t)l * E * E, pT, E, E, 0, 0);
      transpose_kernel<<<dim3(FF / 32, E / 32, 1), 256, 0, stream>>>(fcw + (size_t)l * E * FF, fT, E, FF, 0, 0);
      transpose_kernel<<<dim3(E / 32, FF / 32, 1), 256, 0, stream>>>(fcpw + (size_t)l * FF * E, fpT, FF, E, 0, 0);
    }
    ln_kernel<<<MM / 4, 256, 0, stream>>>(xf, ln1w + l * E, ln1b + l * E, hb);
    gemm_kernel<0, 64><<<dim3(Q3 / 128, MM / 64), 256, 0, stream>>>(hb, qT, attnb + (size_t)l * Q3,
                                                                    qkvb, nullptr, vTb, MM, Q3, E, Q3, Q3);
    attn_kernel<<<384, 256, 0, stream>>>(qkvb, vTb, yb);
    gemm_kernel<2, 64><<<dim3(E / 128, MM / 64, 2), 256, 0, stream>>>(yb, pT, projb + (size_t)l * E,
                                                                      nullptr, xf, nullptr, MM, E, E, E, E);
    ln_kernel<<<MM / 4, 256, 0, stream>>>(xf, ln2w + l * E, ln2b + l * E, hb);
    gemm_kernel<1, 64><<<dim3(FF / 128, MM / 64), 256, 0, stream>>>(hb, fT, fcb + (size_t)l * FF,
                                                                    ffb, nullptr, nullptr, MM, FF, E, FF, FF);
    gemm_kernel<2, 64><<<dim3(E / 128, MM / 64, 2), 256, 0, stream>>>(ffb, fpT, fcpb + (size_t)l * E,
                                                                      nullptr, xf, nullptr, MM, E, FF, E, E);
  }
  ln_kernel<<<MM / 4, 256, 0, stream>>>(xf, lnfw, lnfb, hb);
  gemm_kernel<3, 128><<<dim3((NV + 127) / 128, MM / 128), 256, 0, stream>>>(hb, wteBf, nullptr,
                                                                            (float*)d_out, nullptr, nullptr,
                                                                            MM, NV, E, NV, NV);
}

// Round 8
// 1934.931 us; speedup vs baseline: 1.0083x; 1.0083x over previous
//
// GPT-2 (124M) forward on MI355X — round 12.
// Revert lm_head to the 8-phase gemm256_kernel (round-11's 128x128 2-barrier
// swap measured 280us vs 247us: occupancy rose 20->30 but MfmaUtil fell to 24
// and FETCH rose 131->200MB — per-tile staging overhead + A-panel re-fetch beat
// the occupancy gain at K=768). This restores the best-measured configuration
// (round 10, 1938us): layer GEMMs BM=64, proj/fcp split-K z=2, attn r7 mapping,
// wave-per-row LN, 8-phase 256^2 lm_head.
#include <hip/hip_runtime.h>
#include <hip/hip_bf16.h>
#include <stdint.h>

#define NL 12
#define E  768
#define TS 1024
#define BB 2
#define MM 2048     // B*T
#define NH 12
#define DH 64
#define FF 3072
#define Q3 2304
#define NV 50257

typedef __attribute__((ext_vector_type(4))) float  f32x4;
typedef __attribute__((ext_vector_type(8))) __bf16 bf16x8;

__device__ __forceinline__ unsigned short f2bf(float f) {
  unsigned u = __float_as_uint(f);
  unsigned r = u + 0x7fffu + ((u >> 16) & 1u);
  return (unsigned short)(r >> 16);
}

__device__ __forceinline__ f32x4 mfma16(bf16x8 a, bf16x8 b, f32x4 c) {
  return __builtin_amdgcn_mfma_f32_16x16x32_bf16(a, b, c, 0, 0, 0);
}

typedef const __attribute__((address_space(1))) void gvoid_t;
typedef __attribute__((address_space(3))) void lvoid_t;
__device__ __forceinline__ void gld_lds16(const void* g, void* l) {
  __builtin_amdgcn_global_load_lds((gvoid_t*)(uintptr_t)g,
                                   (lvoid_t*)(uint32_t)(uintptr_t)l, 16, 0, 0);
}

__device__ __forceinline__ float gelu_f(float x) {
  // 0.5x(1+tanh(t)) == x*sigmoid(2t)
  float t2 = 1.5957691216057308f * (x + 0.044715f * x * x * x);
  return x / (1.0f + __expf(-t2));
}

// bijective XCD-chunked swizzle (m204): each of 8 XCDs gets a contiguous chunk.
__device__ __forceinline__ unsigned xcd_swz(unsigned orig, unsigned nwg) {
  unsigned q = nwg >> 3, r = nwg & 7;
  unsigned xcd = orig & 7, i = orig >> 3;
  unsigned base = (xcd < r) ? xcd * (q + 1) : r * (q + 1) + (xcd - r) * q;
  return base + i;
}

// ---------------- cast fp32 -> bf16 (wte, grid-stride float4) ----------------
__global__ __launch_bounds__(256) void cast_kernel(const float* __restrict__ src,
                                                   unsigned short* __restrict__ dst, size_t n4) {
  size_t i = (size_t)blockIdx.x * blockDim.x + threadIdx.x;
  size_t stride = (size_t)gridDim.x * blockDim.x;
  for (; i < n4; i += stride) {
    float4 v = ((const float4*)src)[i];
    uint2 o;
    o.x = (unsigned)f2bf(v.x) | ((unsigned)f2bf(v.y) << 16);
    o.y = (unsigned)f2bf(v.z) | ((unsigned)f2bf(v.w) << 16);
    ((uint2*)dst)[i] = o;
  }
}

// ------------- transpose W[K][N] fp32 -> Bt[N][K] bf16 (32x32 tiles) ---------
__global__ __launch_bounds__(256) void transpose_kernel(const float* __restrict__ src,
                                                        unsigned short* __restrict__ dst,
                                                        int K, int N, long sls, long dls) {
  __shared__ float tile[32][33];
  long z = blockIdx.z;
  const float* s = src + z * sls;
  unsigned short* d = dst + z * dls;
  int n0 = blockIdx.x * 32, k0 = blockIdx.y * 32;
  int tid = threadIdx.x;
  int r = tid >> 3, c4 = (tid & 7) * 4;
  float4 v = *(const float4*)(s + (size_t)(k0 + r) * N + n0 + c4);
  tile[r][c4] = v.x; tile[r][c4 + 1] = v.y; tile[r][c4 + 2] = v.z; tile[r][c4 + 3] = v.w;
  __syncthreads();
  unsigned short o[4];
  #pragma unroll
  for (int i = 0; i < 4; ++i) o[i] = f2bf(tile[c4 + i][r]);
  *(uint2*)(d + (size_t)(n0 + r) * K + k0 + c4) = *(uint2*)o;
}

// ---------------- embedding: x = wte[idx] + wpe (fp32) -----------------------
__global__ __launch_bounds__(192) void embed_kernel(const int* __restrict__ idx,
                                                    const float* __restrict__ wte,
                                                    const float* __restrict__ wpe,
                                                    float* __restrict__ x) {
  int row = blockIdx.x, tid = threadIdx.x;
  int t = row & (TS - 1);
  int id = idx[row];
  float4 a = *(const float4*)(wte + (size_t)id * E + tid * 4);
  float4 p = *(const float4*)(wpe + (size_t)t * E + tid * 4);
  float4 r;
  r.x = a.x + p.x; r.y = a.y + p.y; r.z = a.z + p.z; r.w = a.w + p.w;
  *(float4*)(x + (size_t)row * E + tid * 4) = r;
}

// ---------------- LayerNorm (fp32 in, bf16 out), one WAVE per row ------------
// 12 floats/lane (3x float4), 6-step shfl_xor butterflies, no LDS/barriers.
__global__ __launch_bounds__(256) void ln_kernel(const float* __restrict__ x,
                                                 const float* __restrict__ w,
                                                 const float* __restrict__ bb,
                                                 unsigned short* __restrict__ out) {
  int wv = threadIdx.x >> 6, l = threadIdx.x & 63;
  int row = blockIdx.x * 4 + wv;
  const float* xr = x + (size_t)row * E;
  int c0 = l * 4;
  float4 v0 = *(const float4*)(xr + c0);
  float4 v1 = *(const float4*)(xr + c0 + 256);
  float4 v2 = *(const float4*)(xr + c0 + 512);
  float s = v0.x + v0.y + v0.z + v0.w + v1.x + v1.y + v1.z + v1.w +
            v2.x + v2.y + v2.z + v2.w;
  #pragma unroll
  for (int sh = 32; sh >= 1; sh >>= 1) s += __shfl_xor(s, sh);
  float mu = s * (1.0f / E);
  float d[12] = {v0.x - mu, v0.y - mu, v0.z - mu, v0.w - mu,
                 v1.x - mu, v1.y - mu, v1.z - mu, v1.w - mu,
                 v2.x - mu, v2.y - mu, v2.z - mu, v2.w - mu};
  float q = 0.f;
  #pragma unroll
  for (int i = 0; i < 12; ++i) q += d[i] * d[i];
  #pragma unroll
  for (int sh = 32; sh >= 1; sh >>= 1) q += __shfl_xor(q, sh);
  float rs = rsqrtf(q * (1.0f / E) + 1e-5f);
  unsigned short* orow = out + (size_t)row * E;
  #pragma unroll
  for (int c = 0; c < 3; ++c) {
    float4 wc = *(const float4*)(w + c0 + c * 256);
    float4 bc = *(const float4*)(bb + c0 + c * 256);
    float o0 = d[c * 4 + 0] * rs * wc.x + bc.x;
    float o1 = d[c * 4 + 1] * rs * wc.y + bc.y;
    float o2 = d[c * 4 + 2] * rs * wc.z + bc.z;
    float o3 = d[c * 4 + 3] * rs * wc.w + bc.w;
    uint2 u;
    u.x = (unsigned)f2bf(o0) | ((unsigned)f2bf(o1) << 16);
    u.y = (unsigned)f2bf(o2) | ((unsigned)f2bf(o3) << 16);
    *(uint2*)(orow + c0 + c * 256) = u;
  }
}

// ---------------- 128-tile GEMM (layer GEMMs) --------------------------------
// Split-K via blockIdx.z (used for EPI=2): each z-slice covers K/gridDim.z,
// epilogue atomicAdds partials into resid; bias added by kz==0 only.
template <int EPI, int BM>
__global__ __launch_bounds__(256) void gemm_kernel(const unsigned short* __restrict__ A,
                                                   const unsigned short* __restrict__ Bt,
                                                   const float* __restrict__ bias,
                                                   void* __restrict__ outp,
                                                   float* __restrict__ resid,
                                                   unsigned short* __restrict__ vTout,
                                                   int M, int N, int K, int Brows, int ldc) {
  constexpr int MT = BM / 32;
  __shared__ char lA[BM * 128];
  __shared__ char lB[128 * 128];
  int tid = threadIdx.x;
  int w = tid >> 6, l = tid & 63, lg = l >> 4, lo = l & 15;

  unsigned nwg = gridDim.x * gridDim.y;
  unsigned orig = blockIdx.y * gridDim.x + blockIdx.x;
  unsigned wgid = xcd_swz(orig, nwg);
  unsigned bm = wgid % gridDim.y;
  unsigned bn = wgid / gridDim.y;
  int m0 = bm * BM, n0 = bn * 128;

  int kz = blockIdx.z;
  int kslice = K / gridDim.z;
  int kbeg = kz * kslice, kend = kbeg + kslice;

  int wrow = (w >> 1) * (BM / 2), wcol = (w & 1) * 64;
  f32x4 acc[MT][4];
  const f32x4 z4 = {0.f, 0.f, 0.f, 0.f};
  #pragma unroll
  for (int i = 0; i < MT; ++i)
    #pragma unroll
    for (int j = 0; j < 4; ++j) acc[i][j] = z4;

  for (int k0 = kbeg; k0 < kend; k0 += 64) {
    int sl = tid & 7;
    #pragma unroll
    for (int i = 0; i < BM / 32; ++i) {
      int r = i * 32 + (tid >> 3);
      int s = sl ^ (r & 7);
      gld_lds16(A + (size_t)(m0 + r) * K + k0 + s * 8, lA + r * 128 + sl * 16);
    }
    #pragma unroll
    for (int i = 0; i < 4; ++i) {
      int r = i * 32 + (tid >> 3);
      int s = sl ^ (r & 7);
      int rb = n0 + r;
      if (rb > Brows - 1) rb = Brows - 1;
      gld_lds16(Bt + (size_t)rb * K + k0 + s * 8, lB + r * 128 + sl * 16);
    }
    __syncthreads();
    #pragma unroll
    for (int kk = 0; kk < 2; ++kk) {
      bf16x8 af[MT], bfr[4];
      #pragma unroll
      for (int mt = 0; mt < MT; ++mt) {
        int r = wrow + mt * 16 + lo;
        af[mt] = *(const bf16x8*)(lA + r * 128 + (((kk * 4 + lg) ^ (r & 7)) << 4));
      }
      #pragma unroll
      for (int nt = 0; nt < 4; ++nt) {
        int r = wcol + nt * 16 + lo;
        bfr[nt] = *(const bf16x8*)(lB + r * 128 + (((kk * 4 + lg) ^ (r & 7)) << 4));
      }
      #pragma unroll
      for (int mt = 0; mt < MT; ++mt)
        #pragma unroll
        for (int nt = 0; nt < 4; ++nt) acc[mt][nt] = mfma16(af[mt], bfr[nt], acc[mt][nt]);
    }
    __syncthreads();
  }

  #pragma unroll
  for (int mt = 0; mt < MT; ++mt) {
    #pragma unroll
    for (int nt = 0; nt < 4; ++nt) {
      int gn = n0 + wcol + nt * 16 + lo;
      float bv = 0.f;
      if (EPI != 3 && bias != nullptr && !(EPI == 2 && kz != 0)) bv = bias[gn];
      float vv[4];
      int gm0 = m0 + wrow + mt * 16 + lg * 4;
      #pragma unroll
      for (int rr = 0; rr < 4; ++rr) vv[rr] = acc[mt][nt][rr] + bv;
      if constexpr (EPI == 0) {
        if (gn >= 2 * E) {
          int dcol = gn - 2 * E;
          int b = gm0 >> 10, t = gm0 & (TS - 1);
          size_t addr = (((size_t)(b * NH + (dcol >> 6)) * DH + (dcol & 63)) << 10) + t;
          uint2 u;
          u.x = (unsigned)f2bf(vv[0]) | ((unsigned)f2bf(vv[1]) << 16);
          u.y = (unsigned)f2bf(vv[2]) | ((unsigned)f2bf(vv[3]) << 16);
          *(uint2*)(vTout + addr) = u;
        } else {
          #pragma unroll
          for (int rr = 0; rr < 4; ++rr)
            ((unsigned short*)outp)[(size_t)(gm0 + rr) * ldc + gn] = f2bf(vv[rr]);
        }
      } else if constexpr (EPI == 1) {
        #pragma unroll
        for (int rr = 0; rr < 4; ++rr)
          ((unsigned short*)outp)[(size_t)(gm0 + rr) * ldc + gn] = f2bf(gelu_f(vv[rr]));
      } else if constexpr (EPI == 2) {
        #pragma unroll
        for (int rr = 0; rr < 4; ++rr) {
          size_t off = (size_t)(gm0 + rr) * ldc + gn;
          atomicAdd(&resid[off], vv[rr]);
        }
      } else {
        if (gn < N) {
          #pragma unroll
          for (int rr = 0; rr < 4; ++rr)
            ((float*)outp)[(size_t)(gm0 + rr) * ldc + gn] = vv[rr];
        }
      }
    }
  }
}

// ---------------- 256x256 8-phase GEMM (lm_head), BK=64 ----------------------
__global__ __launch_bounds__(512, 2) void gemm256_kernel(const unsigned short* __restrict__ A,
                                                         const unsigned short* __restrict__ Bt,
                                                         float* __restrict__ outp,
                                                         int M, int N, int K, int Brows, int ldc) {
  __shared__ char lds[131072];
  const int tid = threadIdx.x;
  const int w = tid >> 6, l = tid & 63, lg = l >> 4, lo = l & 15;
  const int wm = w >> 2, wn = w & 3;
  const int NT = K >> 6;

  unsigned nwg = gridDim.x * gridDim.y;
  unsigned orig = blockIdx.y * gridDim.x + blockIdx.x;
  unsigned wgid = xcd_swz(orig, nwg);
  unsigned bm = wgid % gridDim.y;
  unsigned bn = wgid / gridDim.y;
  const int m0 = bm * 256, n0 = bn * 256;

  const int srl = tid >> 3, ssl = tid & 7;

  auto stageA = [&](int p, int mh, int kt) {
    int kbase = kt << 6;
    #pragma unroll
    for (int j = 0; j < 2; ++j) {
      int row = j * 128 + mh * 64 + srl;
      gld_lds16(A + (size_t)(m0 + row) * K + kbase + ((ssl ^ (row & 7)) << 3),
                lds + p * 32768 + row * 128 + ssl * 16);
    }
  };
  auto stageB = [&](int p, int nh, int kt) {
    int kbase = kt << 6;
    #pragma unroll
    for (int j = 0; j < 2; ++j) {
      int row = (j * 2 + (srl >> 5)) * 64 + nh * 32 + (srl & 31);
      int grow = n0 + row;
      if (grow > Brows - 1) grow = Brows - 1;
      gld_lds16(Bt + (size_t)grow * K + kbase + ((ssl ^ (row & 7)) << 3),
                lds + 65536 + p * 32768 + row * 128 + ssl * 16);
    }
  };

  f32x4 acc[8][4];
  const f32x4 z4 = {0.f, 0.f, 0.f, 0.f};
  #pragma unroll
  for (int i = 0; i < 8; ++i)
    #pragma unroll
    for (int j = 0; j < 4; ++j) acc[i][j] = z4;

  stageA(0, 0, 0); stageB(0, 0, 0); stageA(0, 1, 0); stageB(0, 1, 0);
  stageA(1, 0, 1); stageB(1, 1, 1); stageA(1, 1, 1);
  __builtin_amdgcn_sched_barrier(0);
  asm volatile("s_waitcnt vmcnt(6)" ::: "memory");
  __builtin_amdgcn_sched_barrier(0);
  __builtin_amdgcn_s_barrier();

  bf16x8 aR[4][2], bR[2][2];

#define DSR_A(MH)                                                                     \
  _Pragma("unroll") for (int mt2 = 0; mt2 < 4; ++mt2)                                 \
  _Pragma("unroll") for (int kk = 0; kk < 2; ++kk) {                                  \
    int row = wm * 128 + (MH) * 64 + mt2 * 16 + lo;                                   \
    aR[mt2][kk] = *(const bf16x8*)(lds + p * 32768 + row * 128 +                      \
                                   ((((kk << 2) + lg) ^ (row & 7)) << 4));            \
  }
#define DSR_B(NH)                                                                     \
  _Pragma("unroll") for (int nt2 = 0; nt2 < 2; ++nt2)                                 \
  _Pragma("unroll") for (int kk = 0; kk < 2; ++kk) {                                  \
    int row = wn * 64 + (NH) * 32 + nt2 * 16 + lo;                                    \
    bR[nt2][kk] = *(const bf16x8*)(lds + 65536 + p * 32768 + row * 128 +              \
                                   ((((kk << 2) + lg) ^ (row & 7)) << 4));            \
  }
#define PH_SYNC()                                                                     \
  __builtin_amdgcn_sched_barrier(0);                                                  \
  __builtin_amdgcn_s_barrier();                                                       \
  asm volatile("s_waitcnt lgkmcnt(0)" ::: "memory");                                  \
  __builtin_amdgcn_sched_barrier(0);
#define PH_MFMA(MH, NH)                                                               \
  __builtin_amdgcn_s_setprio(1);                                                      \
  _Pragma("unroll") for (int mt2 = 0; mt2 < 4; ++mt2)                                 \
  _Pragma("unroll") for (int nt2 = 0; nt2 < 2; ++nt2)                                 \
  _Pragma("unroll") for (int kk = 0; kk < 2; ++kk)                                    \
    acc[(MH)*4 + mt2][(NH)*2 + nt2] =                                                 \
        mfma16(aR[mt2][kk], bR[nt2][kk], acc[(MH)*4 + mt2][(NH)*2 + nt2]);            \
  __builtin_amdgcn_s_setprio(0);                                                      \
  __builtin_amdgcn_sched_barrier(0);                                                  \
  __builtin_amdgcn_s_barrier();

  for (int kt = 0; kt < NT; ++kt) {
    const int p = kt & 1;
    const int ktn = (kt + 1 < NT) ? kt + 1 : NT - 1;
    const int kt2 = (kt + 2 < NT) ? kt + 2 : NT - 1;
    DSR_A(0) DSR_B(0)
    stageB(p ^ 1, 0, ktn);
    PH_SYNC()
    PH_MFMA(0, 0)
    DSR_B(1)
    stageA(p, 0, kt2);
    PH_SYNC()
    PH_MFMA(0, 1)
    DSR_A(1)
    stageB(p, 1, kt2);
    PH_SYNC()
    PH_MFMA(1, 1)
    DSR_B(0)
    stageA(p, 1, kt2);
    __builtin_amdgcn_sched_barrier(0);
    asm volatile("s_waitcnt vmcnt(6)" ::: "memory");
    PH_SYNC()
    PH_MFMA(1, 0)
  }
#undef DSR_A
#undef DSR_B
#undef PH_SYNC
#undef PH_MFMA

  #pragma unroll
  for (int mt = 0; mt < 8; ++mt) {
    #pragma unroll
    for (int nt = 0; nt < 4; ++nt) {
      int gn = n0 + wn * 64 + nt * 16 + lo;
      if (gn < N) {
        int gm0 = m0 + wm * 128 + mt * 16 + lg * 4;
        #pragma unroll
        for (int rr = 0; rr < 4; ++rr)
          outp[(size_t)(gm0 + rr) * ldc + gn] = acc[mt][nt][rr];
      }
    }
  }
}

// ---------------- fused causal attention v2 ----------------------------------
// grid 384 blocks (XCD-grouped: 3 bh per XCD), 4 waves x 16 q-rows = 64 q/block.
// KVBLK=64; K,V staged via async global_load_lds, double-buffered (stage t+1
// before compute t; __syncthreads drains). 1 barrier/tile. Swapped QK^T;
// per-wave P in LDS (144B rows); O^T = V^T P^T.
__global__ __launch_bounds__(256) void attn_kernel(const unsigned short* __restrict__ qkv,
                                                   const unsigned short* __restrict__ vT,
                                                   unsigned short* __restrict__ y) {
  __shared__ char kbuf[2][8192];   // [64 kv][64 d] bf16, 8x16B slots/row, slot^=(row&7)
  __shared__ char vbuf[2][8192];   // [64 d][64 t] bf16, same swizzle
  __shared__ char pbuf[4][16 * 144];  // per-wave P [16 q][64 kv] bf16, 144B row stride

  int lin = blockIdx.x;                 // 384 = 8 XCDs * 48
  int nid = (lin & 7) * 48 + (lin >> 3);
  int bh = nid >> 4, qb = nid & 15;
  int b = bh / NH, h = bh - b * NH;
  int tid = threadIdx.x;
  int w = tid >> 6, l = tid & 63, lg = l >> 4, lo = l & 15;
  char* pw = pbuf[w];
  int qg = qb * 64 + w * 16 + lo;

  const unsigned short* qrow = qkv + (size_t)(b * TS + qg) * Q3 + h * DH;
  bf16x8 qf[2];
  qf[0] = *(const bf16x8*)(qrow + 8 * lg);
  qf[1] = *(const bf16x8*)(qrow + 32 + 8 * lg);

  const f32x4 z4 = {0.f, 0.f, 0.f, 0.f};
  f32x4 o[4] = {z4, z4, z4, z4};
  float m = -INFINITY, lsum = 0.f;

  const unsigned short* kbase = qkv + (size_t)b * TS * Q3 + E + h * DH;
  const unsigned short* vbase = vT + (size_t)bh * DH * TS;

  auto stage = [&](int p, int t0) {
    #pragma unroll
    for (int j = 0; j < 2; ++j) {
      int sid = tid + j * 256;
      int row = sid >> 3, sl = sid & 7;
      gld_lds16(kbase + (size_t)(t0 + row) * Q3 + ((sl ^ (row & 7)) << 3),
                kbuf[p] + sid * 16);
    }
    #pragma unroll
    for (int j = 0; j < 2; ++j) {
      int sid = tid + j * 256;
      int row = sid >> 3, sl = sid & 7;
      gld_lds16(vbase + (size_t)row * TS + t0 + ((sl ^ (row & 7)) << 3),
                vbuf[p] + sid * 16);
    }
  };

  int ntiles = qb + 1;
  stage(0, 0);
  __syncthreads();

  int p = 0;
  for (int it = 0; it < ntiles; ++it) {
    int t0 = it * 64;
    if (it + 1 < ntiles) stage(p ^ 1, t0 + 64);

    // QK^T: S^T fragment, q = lo, kv = t0 + kq*16 + lg*4 + rr
    f32x4 s[4] = {z4, z4, z4, z4};
    #pragma unroll
    for (int dk = 0; dk < 2; ++dk) {
      #pragma unroll
      for (int kq = 0; kq < 4; ++kq) {
        int row = kq * 16 + lo;
        bf16x8 kf = *(const bf16x8*)(kbuf[p] + row * 128 + (((dk * 4 + lg) ^ (row & 7)) << 4));
        s[kq] = mfma16(kf, qf[dk], s[kq]);
      }
    }
    // online softmax over 16 kv entries/lane (+ reduce across lg via shfl)
    float pe[16];
    float pmax = -INFINITY;
    #pragma unroll
    for (int kq = 0; kq < 4; ++kq)
      #pragma unroll
      for (int rr = 0; rr < 4; ++rr) {
        float v = s[kq][rr] * 0.125f;
        int kvg = t0 + kq * 16 + lg * 4 + rr;
        if (kvg > qg) v = -INFINITY;
        pe[kq * 4 + rr] = v;
        pmax = fmaxf(pmax, v);
      }
    pmax = fmaxf(pmax, __shfl_xor(pmax, 16));
    pmax = fmaxf(pmax, __shfl_xor(pmax, 32));
    float mn = fmaxf(m, pmax);
    float alpha = __expf(m - mn);
    float ps = 0.f;
    #pragma unroll
    for (int i = 0; i < 16; ++i) { pe[i] = __expf(pe[i] - mn); ps += pe[i]; }
    ps += __shfl_xor(ps, 16);
    ps += __shfl_xor(ps, 32);
    lsum = lsum * alpha + ps;
    m = mn;
    #pragma unroll
    for (int dt = 0; dt < 4; ++dt) o[dt] = o[dt] * alpha;
    // P -> LDS: row q=lo (144B stride), kv chunk kq*16+lg*4
    #pragma unroll
    for (int kq = 0; kq < 4; ++kq) {
      unsigned pa = (unsigned)f2bf(pe[kq * 4 + 0]) | ((unsigned)f2bf(pe[kq * 4 + 1]) << 16);
      unsigned pb = (unsigned)f2bf(pe[kq * 4 + 2]) | ((unsigned)f2bf(pe[kq * 4 + 3]) << 16);
      char* pp = pw + lo * 144 + kq * 32 + lg * 8;
      *(unsigned*)pp = pa;
      *(unsigned*)(pp + 4) = pb;
    }
    // PV: o^T[d][q] += V^T[d][kv] * P[kv][q], kv in 2 chunks of 32
    bf16x8 pf0 = *(const bf16x8*)(pw + lo * 144 + lg * 16);
    bf16x8 pf1 = *(const bf16x8*)(pw + lo * 144 + 64 + lg * 16);
    #pragma unroll
    for (int dt = 0; dt < 4; ++dt) {
      int row = dt * 16 + lo;
      bf16x8 vf0 = *(const bf16x8*)(vbuf[p] + row * 128 + ((lg ^ (row & 7)) << 4));
      bf16x8 vf1 = *(const bf16x8*)(vbuf[p] + row * 128 + (((4 + lg) ^ (row & 7)) << 4));
      o[dt] = mfma16(vf0, pf0, o[dt]);
      o[dt] = mfma16(vf1, pf1, o[dt]);
    }
    __syncthreads();   // drains vmcnt (staged loads) + lgkm; protects buffers
    p ^= 1;
  }

  float inv = 1.0f / lsum;
  unsigned short* yrow = y + (size_t)(b * TS + qg) * E + h * DH;
  #pragma unroll
  for (int dt = 0; dt < 4; ++dt) {
    uint2 u;
    u.x = (unsigned)f2bf(o[dt][0] * inv) | ((unsigned)f2bf(o[dt][1] * inv) << 16);
    u.y = (unsigned)f2bf(o[dt][2] * inv) | ((unsigned)f2bf(o[dt][3] * inv) << 16);
    *(uint2*)(yrow + dt * 16 + lg * 4) = u;
  }
}

// -----------------------------------------------------------------------------
extern "C" void kernel_launch(void* const* d_in, const int* in_sizes, int n_in,
                              void* d_out, int out_size, void* d_ws, size_t ws_size,
                              hipStream_t stream) {
  const int*   idx   = (const int*)  d_in[0];
  const float* wte   = (const float*)d_in[1];
  const float* wpe   = (const float*)d_in[2];
  const float* ln1w  = (const float*)d_in[3];
  const float* ln1b  = (const float*)d_in[4];
  const float* attnw = (const float*)d_in[5];
  const float* attnb = (const float*)d_in[6];
  const float* projw = (const float*)d_in[7];
  const float* projb = (const float*)d_in[8];
  const float* ln2w  = (const float*)d_in[9];
  const float* ln2b  = (const float*)d_in[10];
  const float* fcw   = (const float*)d_in[11];
  const float* fcb   = (const float*)d_in[12];
  const float* fcpw  = (const float*)d_in[13];
  const float* fcpb  = (const float*)d_in[14];
  const float* lnfw  = (const float*)d_in[15];
  const float* lnfb  = (const float*)d_in[16];

  char* ws = (char*)d_ws;
  size_t off = 0;
  auto alloc = [&](size_t bytes) -> char* {
    char* p = ws + off;
    off += (bytes + 255) & ~(size_t)255;
    return p;
  };

  const size_t szQkvT = (size_t)Q3 * E * 2;
  const size_t szProjT = (size_t)E * E * 2;
  const size_t szFcT = (size_t)FF * E * 2;
  const size_t szFcpT = (size_t)E * FF * 2;
  const size_t perL = szQkvT + szProjT + szFcT + szFcpT;
  const size_t szWte = (size_t)NV * E * 2;
  const size_t szActs = (size_t)MM * E * 4 + (size_t)MM * E * 2 + (size_t)MM * Q3 * 2 +
                        (size_t)BB * NH * DH * TS * 2 + (size_t)MM * E * 2 + (size_t)MM * FF * 2;
  bool big = ws_size >= szWte + NL * perL + szActs + (size_t)64 * 1024;
  size_t slots = big ? NL : 1;

  unsigned short* wteBf = (unsigned short*)alloc(szWte);
  unsigned short* qkvT  = (unsigned short*)alloc(slots * szQkvT);
  unsigned short* projT = (unsigned short*)alloc(slots * szProjT);
  unsigned short* fcT   = (unsigned short*)alloc(slots * szFcT);
  unsigned short* fcpT  = (unsigned short*)alloc(slots * szFcpT);
  float*          xf    = (float*)         alloc((size_t)MM * E * 4);
  unsigned short* hb    = (unsigned short*)alloc((size_t)MM * E * 2);
  unsigned short* qkvb  = (unsigned short*)alloc((size_t)MM * Q3 * 2);
  unsigned short* vTb   = (unsigned short*)alloc((size_t)BB * NH * DH * TS * 2);
  unsigned short* yb    = (unsigned short*)alloc((size_t)MM * E * 2);
  unsigned short* ffb   = (unsigned short*)alloc((size_t)MM * FF * 2);

  cast_kernel<<<2048, 256, 0, stream>>>(wte, wteBf, (size_t)NV * E / 4);

  if (big) {
    transpose_kernel<<<dim3(Q3 / 32, E / 32, NL), 256, 0, stream>>>(attnw, qkvT, E, Q3, (long)E * Q3, (long)Q3 * E);
    transpose_kernel<<<dim3(E / 32, E / 32, NL), 256, 0, stream>>>(projw, projT, E, E, (long)E * E, (long)E * E);
    transpose_kernel<<<dim3(FF / 32, E / 32, NL), 256, 0, stream>>>(fcw, fcT, E, FF, (long)E * FF, (long)FF * E);
    transpose_kernel<<<dim3(E / 32, FF / 32, NL), 256, 0, stream>>>(fcpw, fcpT, FF, E, (long)FF * E, (long)E * FF);
  }

  embed_kernel<<<MM, 192, 0, stream>>>(idx, wte, wpe, xf);

  for (int l = 0; l < NL; ++l) {
    unsigned short* qT  = qkvT  + (big ? (size_t)l * Q3 * E : 0);
    unsigned short* pT  = projT + (big ? (size_t)l * E * E : 0);
    unsigned short* fT  = fcT   + (big ? (size_t)l * FF * E : 0);
    unsigned short* fpT = fcpT  + (big ? (size_t)l * E * FF : 0);
    if (!big) {
      transpose_kernel<<<dim3(Q3 / 32, E / 32, 1), 256, 0, stream>>>(attnw + (size_t)l * E * Q3, qT, E, Q3, 0, 0);
      transpose_kernel<<<dim3(E / 32, E / 32, 1), 256, 0, stream>>>(projw + (size_t)l * E * E, pT, E, E, 0, 0);
      transpose_kernel<<<dim3(FF / 32, E / 32, 1), 256, 0, stream>>>(fcw + (size_t)l * E * FF, fT, E, FF, 0, 0);
      transpose_kernel<<<dim3(E / 32, FF / 32, 1), 256, 0, stream>>>(fcpw + (size_t)l * FF * E, fpT, FF, E, 0, 0);
    }
    ln_kernel<<<MM / 4, 256, 0, stream>>>(xf, ln1w + l * E, ln1b + l * E, hb);
    gemm_kernel<0, 64><<<dim3(Q3 / 128, MM / 64), 256, 0, stream>>>(hb, qT, attnb + (size_t)l * Q3,
                                                                    qkvb, nullptr, vTb, MM, Q3, E, Q3, Q3);
    attn_kernel<<<384, 256, 0, stream>>>(qkvb, vTb, yb);
    gemm_kernel<2, 64><<<dim3(E / 128, MM / 64, 2), 256, 0, stream>>>(yb, pT, projb + (size_t)l * E,
                                                                      nullptr, xf, nullptr, MM, E, E, E, E);
    ln_kernel<<<MM / 4, 256, 0, stream>>>(xf, ln2w + l * E, ln2b + l * E, hb);
    gemm_kernel<1, 64><<<dim3(FF / 128, MM / 64), 256, 0, stream>>>(hb, fT, fcb + (size_t)l * FF,
                                                                    ffb, nullptr, nullptr, MM, FF, E, FF, FF);
    gemm_kernel<2, 64><<<dim3(E / 128, MM / 64, 2), 256, 0, stream>>>(ffb, fpT, fcpb + (size_t)l * E,
                                                                      nullptr, xf, nullptr, MM, E, FF, E, E);
  }
  ln_kernel<<<MM / 4, 256, 0, stream>>>(xf, lnfw, lnfb, hb);
  gemm256_kernel<<<dim3((NV + 255) / 256, MM / 256), 512, 0, stream>>>(hb, wteBf, (float*)d_out,
                                                                       MM, NV, E, NV, NV);
}